// Round 3
// baseline (115.235 us; speedup 1.0000x reference)
//
#include <hip/hip_runtime.h>
#include <math.h>

// PrecisionFocusedLoss: mean over B of ce(logits, t) * (1 + 3*penalty)
//   penalty: FN (t==1, p==0) -> 1.0 ; FP (t==0, p==1) -> 5.0 ; else 0.1
//   => weight: FN -> 4.0 ; FP -> 16.0 ; else 1.3
// B = 8388608, C = 2. Memory-bound: 100.7 MB in, 4 B out. Roofline ~16 us @ 6.3 TB/s.
//
// v4: all loads perfectly unit-stride per instruction.
//     v3 loaded logits4[2q], logits4[2q+1] per thread: 32 B lane stride per
//     dwordx4 -> only 2 lanes per 64 B line per instruction (2x TA/L1
//     transactions). Now targets come as int2 so each thread maps 1:1 to a
//     float4: lane i reads base + 16*i (logits) / base + 8*i (targets) --
//     every load instruction is a single fully-coalesced wave transaction.
//     8 float4 + 8 int2 per thread, all issued before any compute.

#define LOSS_BATCH 8388608
#define LOSS_GRID  2048
#define LOSS_BLOCK 256
#define LOSS_THREADS (LOSS_GRID * LOSS_BLOCK)   // 524288
#define F4_PER_THREAD 8                         // 524288*8 = 4194304 = B/2 float4s exactly

__device__ __forceinline__ float sample_loss(float l0, float l1, int t) {
    // log-sum-exp over 2 classes, numerically stable:
    // lse = max + softplus(-|l0-l1|), softplus(x) = log(1+exp(x))
    float m  = fmaxf(l0, l1);
    float d  = fabsf(l0 - l1);
    float sp = __logf(1.0f + __expf(-d));   // native v_exp_f32 / v_log_f32
    float ce = (m + sp) - (t ? l1 : l0);
    // argmax with first-index tie-break: pred=1 iff l1 > l0
    bool p1 = l1 > l0;
    float w = 1.3f;                          // 1 + 3*0.1
    if (t) { if (!p1) w = 4.0f;  }           // false negative: 1 + 3*1.0
    else   { if (p1)  w = 16.0f; }           // false positive: 1 + 3*5.0
    return ce * w;
}

__global__ __launch_bounds__(LOSS_BLOCK) void loss_partial_kernel(
        const float4* __restrict__ logits4,   // 2 samples per float4
        const int2*   __restrict__ tgt2,      // 2 targets per int2, 1:1 with float4
        float*        __restrict__ partials)  // [LOSS_GRID]
{
    const int tid = blockIdx.x * LOSS_BLOCK + threadIdx.x;

    // 16 independent, fully-coalesced loads in flight per thread.
    float4 f[F4_PER_THREAD];
    int2   t[F4_PER_THREAD];
    #pragma unroll
    for (int k = 0; k < F4_PER_THREAD; ++k) {
        const int q = tid + k * LOSS_THREADS;
        f[k] = logits4[q];
        t[k] = tgt2[q];
    }

    float acc = 0.0f;
    #pragma unroll
    for (int k = 0; k < F4_PER_THREAD; ++k) {
        acc += sample_loss(f[k].x, f[k].y, t[k].x);
        acc += sample_loss(f[k].z, f[k].w, t[k].y);
    }

    // wave-64 reduction
    #pragma unroll
    for (int off = 32; off > 0; off >>= 1)
        acc += __shfl_down(acc, off, 64);
    __shared__ float smem[LOSS_BLOCK / 64];
    const int lane = threadIdx.x & 63;
    const int wid  = threadIdx.x >> 6;
    if (lane == 0) smem[wid] = acc;
    __syncthreads();
    if (threadIdx.x == 0)
        partials[blockIdx.x] = smem[0] + smem[1] + smem[2] + smem[3];
}

__global__ __launch_bounds__(256) void loss_final_kernel(
        const float* __restrict__ partials, float* __restrict__ out)
{
    double acc = 0.0;
    #pragma unroll
    for (int i = 0; i < LOSS_GRID / 256; ++i)
        acc += (double)partials[threadIdx.x + i * 256];
    #pragma unroll
    for (int off = 32; off > 0; off >>= 1)
        acc += __shfl_down(acc, off, 64);
    __shared__ double smem[4];
    const int lane = threadIdx.x & 63;
    const int wid  = threadIdx.x >> 6;
    if (lane == 0) smem[wid] = acc;
    __syncthreads();
    if (threadIdx.x == 0) {
        double s = smem[0] + smem[1] + smem[2] + smem[3];
        out[0] = (float)(s / (double)LOSS_BATCH);
    }
}

extern "C" void kernel_launch(void* const* d_in, const int* in_sizes, int n_in,
                              void* d_out, int out_size, void* d_ws, size_t ws_size,
                              hipStream_t stream) {
    const float4* logits4 = (const float4*)d_in[0];
    const int2*   tgt2    = (const int2*)d_in[1];
    float* partials = (float*)d_ws;           // LOSS_GRID floats = 8 KB
    float* out      = (float*)d_out;

    loss_partial_kernel<<<LOSS_GRID, LOSS_BLOCK, 0, stream>>>(logits4, tgt2, partials);
    loss_final_kernel<<<1, 256, 0, stream>>>(partials, out);
}